// Round 10
// baseline (276.826 us; speedup 1.0000x reference)
//
#include <hip/hip_runtime.h>

// DropBlock + LIF forward, two kernels (R10: 8-chunk wave fattening).
// x: [T*bs, C, H, W] = [160, 64, 64, 64] f32, mask_rand: [160, 64, 64] f32
// out: [160, 64, 64, 64] f32
//
// Scoreboard: R9 (NT, 4-chunk, 2048 blk) 274.5 BEST | R8 (2-chunk) 278.0 |
// R0 (1-chunk) 280.6 | R5 (plain) 288.9 | R1 (grid-stride) 295.1 |
// R4 (strided 32B/thr) 295.6.
// Lessons: NT wins; per-INSTRUCTION 1KB-solid wave footprint mandatory;
// minimal streams/thread; fattening 1->2->4 gained 2.6+3.5 µs (not yet
// diminishing). R10: 8 chunks/thread (+0..+7 KB). 1024 blocks = 4 blk/CU =
// 16 waves/CU -> single resident pass even at the 128-VGPR step; 8 KB
// contiguous per wave per stream; 40 NT loads in flight/thread.
//
// Stage 1 (bm_bits_kernel): per row (one wave each), dropblock row-mask as a
//   64-bit word: 7 clipped vertical loads/lane -> OR -> __ballot (vertical
//   dilate) -> bit smear +/-3 (horizontal dilate). Set bit = dropped.
// Stage 2 (lif_kernel): u = (u>1 ? 0 : 0.5u) + x_t (bitwise equal to
//   tau*u*(1-spike)+x), o_t = (u>1 && !dropped) ? 1 : 0.

#define TSTEPS 5
#define BSZ 32
#define CHN 64
#define HH 64
#define WW 64

typedef float v4f __attribute__((ext_vector_type(4)));

__global__ __launch_bounds__(256) void bm_bits_kernel(const float* __restrict__ mr,
                                                      unsigned long long* __restrict__ bmbits) {
    // one wave (64 lanes) per row; 4 waves per block; rows = T*bs*HH = 10240
    const float GAMMA = (float)(0.1 / 49.0);  // matches JAX weak-type promotion
    int row = blockIdx.x * 4 + (threadIdx.x >> 6);  // [0, 10240)
    int lane = threadIdx.x & 63;                    // pixel w
    int h = row & (HH - 1);
    int n = row >> 6;  // plane id in [0, T*bs)

    const float* base = mr + (size_t)n * (HH * WW) + lane;
    bool drop = false;
#pragma unroll
    for (int dh = -3; dh <= 3; ++dh) {
        int hh = h + dh;
        if (hh >= 0 && hh < HH) drop = drop || (base[hh * WW] < GAMMA);
    }
    unsigned long long m = __ballot(drop);  // bit w = column drop (vertical done)
    unsigned long long s = m | (m << 1) | (m << 2) | (m << 3)
                             | (m >> 1) | (m >> 2) | (m >> 3);
    if (lane == 0) bmbits[row] = s;  // set bit => dropped => output 0
}

__global__ __launch_bounds__(256) void lif_kernel(const float* __restrict__ x,
                                                  const unsigned long long* __restrict__ bmbits,
                                                  float* __restrict__ o) {
    // Each wave owns EIGHT adjacent 64-float4 chunks (8 KB contiguous per t).
    // Thread g: f(k) = (g&~63)*8 + lane + k*64, k=0..7 (float4 indices).
    // Chunk-group = 512 float4 = half a plane -> never straddles a plane.
    const int HW4 = HH * WW / 4;  // 1024 float4 groups per plane
    int g = blockIdx.x * blockDim.x + threadIdx.x;  // [0, 262144)
    int lane = g & 63;
    int f0 = ((g & ~63) << 3) + lane;  // float4 index of chunk0 element

    int hw4 = f0 & (HW4 - 1);
    int c = (f0 >> 10) & (CHN - 1);
    int b = f0 >> 16;
    if (b >= BSZ) return;

    int h0 = hw4 >> 4;        // row of chunk0 (chunk k row = h0 + 4k, <= 63)
    int sh = (hw4 & 15) * 4;  // same nibble shift for all chunks

    size_t xoff = (((size_t)b * CHN + c) * (size_t)(HH * WW)) + (size_t)hw4 * 4;
    const size_t XT = (size_t)BSZ * CHN * HH * WW;  // x/o time stride (floats)
    int mrow = b * HH + h0;                         // chunk k mask row = +4k
    const int MT = BSZ * HH;

    v4f u[8];
#pragma unroll
    for (int k = 0; k < 8; ++k) u[k] = (v4f){0.f, 0.f, 0.f, 0.f};

#pragma unroll
    for (int t = 0; t < TSTEPS; ++t) {
        const float* xp = x + xoff + (size_t)t * XT;
        float* op = o + xoff + (size_t)t * XT;
        v4f xv[8];
#pragma unroll
        for (int k = 0; k < 8; ++k)
            xv[k] = __builtin_nontemporal_load((const v4f*)(xp + k * 256));
        unsigned int nib[8];
#pragma unroll
        for (int k = 0; k < 8; ++k)
            nib[k] = (unsigned int)((bmbits[mrow + 4 * k + t * MT] >> sh) & 0xFull);
#pragma unroll
        for (int k = 0; k < 8; ++k) {
            v4f ov;
#pragma unroll
            for (int j = 0; j < 4; ++j) {
                u[k][j] = (u[k][j] > 1.0f ? 0.0f : 0.5f * u[k][j]) + xv[k][j];
                ov[j] = (u[k][j] > 1.0f && !(nib[k] & (1u << j))) ? 1.0f : 0.0f;
            }
            __builtin_nontemporal_store(ov, (v4f*)(op + k * 256));
        }
    }
}

extern "C" void kernel_launch(void* const* d_in, const int* in_sizes, int n_in,
                              void* d_out, int out_size, void* d_ws, size_t ws_size,
                              hipStream_t stream) {
    const float* x = (const float*)d_in[0];
    const float* mask_rand = (const float*)d_in[1];
    float* out = (float*)d_out;
    unsigned long long* bmbits = (unsigned long long*)d_ws;  // 10240 * 8 B = 80 KB

    const int bm_rows = TSTEPS * BSZ * HH;                  // 10240 rows (1 wave each)
    const int lif_threads = BSZ * CHN * (HH * WW / 4) / 8;  // 262,144

    bm_bits_kernel<<<bm_rows / 4, 256, 0, stream>>>(mask_rand, bmbits);
    lif_kernel<<<lif_threads / 256, 256, 0, stream>>>(x, bmbits, out);
}